// Round 1
// baseline (898.047 us; speedup 1.0000x reference)
//
#include <hip/hip_runtime.h>
#include <cstdint>
#include <cstddef>

// Net: out = sign( BN_train( sign(x)@sign(W1)^T ) clipped ) @ sign(W4)^T
// B=8192, K=16384, H=384, O=10.  All values exact small integers.
//
// R3 structure: the per-iteration __syncthreads + vmcnt(0) drain in gemm1 was
// the bottleneck (every wave on the CU stalled on the HBM x-load each K-step).
// Fix: binarize x ONCE in a streaming prep pass into fp8 with the same 16B
// fragment-granule layout as W1c. gemm1 then needs NO LDS and NO barriers:
// each lane loads its A fragment pair with one dwordx4, register
// double-buffers both operands, and the compiler/wave-scheduler hides latency
// freely across 4 blocks/CU. kblk = blockIdx&3 pins one W1c K-chunk per XCD
// (xcd = blockIdx%8) so W streams from per-XCD L2.

typedef float v4f __attribute__((ext_vector_type(4)));
typedef long long v2l __attribute__((ext_vector_type(2)));

#define BATCH   8192
#define KDIM    16384
#define HID     384
#define OUT_F   10
#define BK      64
#define MT      32
#define SPLITK  4
#define KPB     (KDIM / SPLITK)      // 4096
#define NIT     (KPB / BK)           // 64
#define WCHUNK  (HID * BK)           // 24576 B of fp8 W1 per K-chunk

// ---- ws layout (bytes) ----
#define WS_W1C   0
#define WS_H     (6291456)                  // float h[8192][384] = 12582912 B
#define WS_GSUM  (WS_H + 12582912)          // double[384]
#define WS_GSQ   (WS_GSUM + 3072)           // double[384]
#define WS_MEAN  (WS_GSQ + 3072)            // double[384]
#define WS_COEF  (WS_MEAN + 3072)           // double[384]
#define WS_SW4   (WS_COEF + 3072)           // float[3840]
#define WS_XB    (WS_SW4 + 15360)           // uint8 xb[8192*16384] = 134217728 B

__device__ __forceinline__ uint32_t pack_sign4(v4f v) {
    uint32_t p = 0;
#pragma unroll
    for (int i = 0; i < 4; ++i) {
        uint32_t u = __float_as_uint(v[i]);
        // +1 -> 0x38, -1 -> 0xB8 (fp8 e4m3), exact 0 stays 0 (matches jnp.sign)
        uint32_t b = ((u & 0x7fffffffu) == 0u) ? 0u : (0x38u | ((u >> 24) & 0x80u));
        p |= b << (8 * i);
    }
    return p;
}

// K0a: binarize W1 -> fp8, layout [it(256)][col(384)][q(4)][16B], where the
// 16B granule for (col,q) = k-bytes {q*8..q*8+7} ++ {32+q*8..32+q*8+7}.
// Lane (q,l15) of a wave then loads its whole 16x16x32 B-fragment pair
// (s=0,1) with ONE dwordx4.
__global__ void prep_w1(const float* __restrict__ W1, uint8_t* __restrict__ W1c) {
    size_t e = ((size_t)blockIdx.x * blockDim.x + threadIdx.x) * 4;
    int c   = (int)(e >> 14);         // / 16384
    int k   = (int)(e & 16383);
    int it  = k >> 6;
    int kin = k & 63;
    int s   = kin >> 5;
    int q   = (kin >> 3) & 3;
    int j   = kin & 7;                // 0 or 4
    v4f w = *(const v4f*)(W1 + e);
    uint32_t p = pack_sign4(w);
    *(uint32_t*)(W1c + (((size_t)it * HID + c) * 4 + q) * 16 + s * 8 + j) = p;
}

// K0b: binarize x -> fp8 in A-fragment granule layout:
// xb[mblk(256)][itg(256)][row(32)][granule 64B: byte = q*16 + s*8 + j]
// where source k = itg*64 + s*32 + q*8 + j.  One thread packs 8 consecutive
// k (fixed s,q) -> one 8B write; a wave writes 512 contiguous bytes.
__global__ void prep_x(const float* __restrict__ x, uint8_t* __restrict__ xb) {
    size_t g = (size_t)blockIdx.x * blockDim.x + threadIdx.x;
    int k8  = ((int)g & 7) * 8;       // 0..56
    int r   = ((int)(g >> 3)) & 31;   // row within mblk
    int itg = ((int)(g >> 8)) & 255;
    int mb  = (int)(g >> 16);         // 0..255
    int row = mb * 32 + r;
    int k   = itg * 64 + k8;
    const float* px = x + (size_t)row * KDIM + k;
    v4f a = *(const v4f*)px;
    v4f b = *(const v4f*)(px + 4);
    int s = k8 >> 5;
    int q = (k8 >> 3) & 3;
    uint2 p;
    p.x = pack_sign4(a);
    p.y = pack_sign4(b);
    *(uint2*)(xb + (((size_t)mb * 256 + itg) * 32 + r) * 64 + q * 16 + s * 8) = p;
}

// K1: binary GEMM, barrier-free. grid = (8192/32)*SPLITK = 1024 blocks x 256
// threads = 4 blocks/CU. Each wave owns 96 columns (6 n-tiles) x 32 rows.
// Both operands live in registers, double-buffered; no LDS, no __syncthreads.
__global__ __launch_bounds__(256, 4) void gemm1(const uint8_t* __restrict__ xb,
                                                const uint8_t* __restrict__ W1c,
                                                float* __restrict__ h) {
    const int t    = threadIdx.x;
    const int wave = t >> 6;
    const int lane = t & 63;
    const int q    = lane >> 4;    // 0..3
    const int l15  = lane & 15;
    const int kblk = blockIdx.x & (SPLITK - 1);   // == (blockIdx%8)%4 -> one W chunk per XCD
    const int m0   = (blockIdx.x >> 2) * MT;

    // per-lane A base: block's x region is contiguous 128KB
    const uint8_t* xp = xb + ((size_t)(blockIdx.x >> 2) * 256 + (size_t)kblk * NIT) * 2048
                      + (size_t)l15 * 64 + q * 16;
    // per-lane B base (iter stride = WCHUNK, nt stride = 1024B)
    const uint8_t* wp = W1c + (size_t)kblk * ((size_t)NIT * WCHUNK)
                      + (((size_t)(wave * 96 + l15)) * 4 + q) * 16;

    v4f acc[2][6];
#pragma unroll
    for (int mt = 0; mt < 2; ++mt)
#pragma unroll
        for (int nt = 0; nt < 6; ++nt)
            acc[mt][nt] = v4f{0.f, 0.f, 0.f, 0.f};

    v2l wc[6], xc[2];
#pragma unroll
    for (int nt = 0; nt < 6; ++nt) wc[nt] = *(const v2l*)(wp + nt * 1024);
    xc[0] = *(const v2l*)(xp);
    xc[1] = *(const v2l*)(xp + 1024);        // mt=1: +16 rows * 64B

#define COMPUTE_STEP                                                         \
    _Pragma("unroll")                                                        \
    for (int s = 0; s < 2; ++s)                                              \
        _Pragma("unroll")                                                    \
        for (int nt = 0; nt < 6; ++nt)                                       \
            _Pragma("unroll")                                                \
            for (int mt = 0; mt < 2; ++mt)                                   \
                acc[mt][nt] = __builtin_amdgcn_mfma_f32_16x16x32_fp8_fp8(    \
                    xc[mt][s], wc[nt][s], acc[mt][nt], 0, 0, 0);

#pragma unroll 2
    for (int it = 0; it < NIT - 1; ++it) {
        v2l wn[6], xn[2];
        const uint8_t* wpn = wp + (size_t)(it + 1) * WCHUNK;
        const uint8_t* xpn = xp + (size_t)(it + 1) * 2048;
#pragma unroll
        for (int nt = 0; nt < 6; ++nt) wn[nt] = *(const v2l*)(wpn + nt * 1024);
        xn[0] = *(const v2l*)(xpn);
        xn[1] = *(const v2l*)(xpn + 1024);

        COMPUTE_STEP

#pragma unroll
        for (int nt = 0; nt < 6; ++nt) wc[nt] = wn[nt];
        xc[0] = xn[0];
        xc[1] = xn[1];
    }
    COMPUTE_STEP
#undef COMPUTE_STEP

    // epilogue: C/D layout col=lane&15, row=(lane>>4)*4+reg  [m89/m121]
    // split-K partials are integers |p|<=4096 -> fp32 atomicAdd is exact.
#pragma unroll
    for (int nt = 0; nt < 6; ++nt) {
        const int col = wave * 96 + nt * 16 + l15;
#pragma unroll
        for (int mt = 0; mt < 2; ++mt)
#pragma unroll
            for (int r = 0; r < 4; ++r)
                atomicAdd(&h[(size_t)(m0 + mt * 16 + q * 4 + r) * HID + col],
                          acc[mt][nt][r]);
    }
}

// K2: per-column sum / sumsq in fp64 (exact: integer values). 512 blocks.
__global__ void colstats(const float* __restrict__ h,
                         double* __restrict__ gsum, double* __restrict__ gsq) {
    int j  = threadIdx.x;          // 0..383, coalesced
    int r0 = blockIdx.x * 16;
    double s = 0.0, sq = 0.0;
#pragma unroll
    for (int r = 0; r < 16; ++r) {
        double v = (double)h[(size_t)(r0 + r) * HID + j];
        s += v;
        sq += v * v;
    }
    atomicAdd(&gsum[j], s);
    atomicAdd(&gsq[j], sq);
}

// K2b: finalize stats + sign(W4) table
__global__ void finalize(const double* __restrict__ gsum, const double* __restrict__ gsq,
                         const float* __restrict__ gamma, const float* __restrict__ W4,
                         double* __restrict__ meanArr, double* __restrict__ coefArr,
                         float* __restrict__ sW4) {
    int j = threadIdx.x;
    double mean = gsum[j] * (1.0 / (double)BATCH);
    double var  = gsq[j] * (1.0 / (double)BATCH) - mean * mean;
    meanArr[j] = mean;
    coefArr[j] = (double)gamma[j] / sqrt(var + 1e-5);
#pragma unroll
    for (int o = 0; o < OUT_F; ++o) {
        float w = W4[o * HID + j];
        sW4[o * HID + j] = (w > 0.f) ? 1.f : ((w < 0.f) ? -1.f : 0.f);
    }
}

// K3: per-row normalize -> sign -> tiny GEMM with sign(W4). One wave per row.
__global__ __launch_bounds__(256) void head(const float* __restrict__ h,
                                            const double* __restrict__ meanArr,
                                            const double* __restrict__ coefArr,
                                            const float* __restrict__ beta,
                                            const float* __restrict__ sW4,
                                            float* __restrict__ out) {
    int wave = threadIdx.x >> 6;
    int lane = threadIdx.x & 63;
    int b = blockIdx.x * 4 + wave;
    float a[OUT_F];
#pragma unroll
    for (int o = 0; o < OUT_F; ++o) a[o] = 0.f;
#pragma unroll
    for (int i = 0; i < 6; ++i) {
        int j = lane + i * 64;
        double v = ((double)h[(size_t)b * HID + j] - meanArr[j]) * coefArr[j]
                 + (double)beta[j];
        // clip(-1,1) preserves sign; sign(0)=0
        float s = (v > 0.0) ? 1.f : ((v < 0.0) ? -1.f : 0.f);
#pragma unroll
        for (int o = 0; o < OUT_F; ++o) a[o] += s * sW4[o * HID + j];
    }
#pragma unroll
    for (int o = 0; o < OUT_F; ++o) {
#pragma unroll
        for (int off = 32; off > 0; off >>= 1) a[o] += __shfl_down(a[o], off);
    }
    if (lane == 0) {
#pragma unroll
        for (int o = 0; o < OUT_F; ++o) out[(size_t)b * OUT_F + o] = a[o];
    }
}

extern "C" void kernel_launch(void* const* d_in, const int* in_sizes, int n_in,
                              void* d_out, int out_size, void* d_ws, size_t ws_size,
                              hipStream_t stream) {
    const float* x     = (const float*)d_in[0];
    const float* W1    = (const float*)d_in[1];
    const float* gamma = (const float*)d_in[2];
    const float* beta  = (const float*)d_in[3];
    const float* W4    = (const float*)d_in[4];
    float* out = (float*)d_out;

    uint8_t* ws = (uint8_t*)d_ws;
    uint8_t* W1c     = ws + WS_W1C;
    float*   h       = (float*)(ws + WS_H);
    double*  gsum    = (double*)(ws + WS_GSUM);
    double*  gsq     = (double*)(ws + WS_GSQ);
    double*  meanArr = (double*)(ws + WS_MEAN);
    double*  coefArr = (double*)(ws + WS_COEF);
    float*   sW4     = (float*)(ws + WS_SW4);
    uint8_t* xb      = ws + WS_XB;

    prep_w1<<<6144, 256, 0, stream>>>(W1, W1c);
    prep_x<<<65536, 256, 0, stream>>>(x, xb);
    // zero h (needed: split-K atomic accumulate) + gsum + gsq in one memset
    hipMemsetAsync(ws + WS_H, 0, 12582912 + 2 * HID * sizeof(double), stream);
    gemm1<<<(BATCH / MT) * SPLITK, 256, 0, stream>>>(xb, W1c, h);
    colstats<<<BATCH / 16, HID, 0, stream>>>(h, gsum, gsq);
    finalize<<<1, HID, 0, stream>>>(gsum, gsq, gamma, W4, meanArr, coefArr, sW4);
    head<<<BATCH / 4, 256, 0, stream>>>(h, meanArr, coefArr, beta, sW4, out);
}